// Round 14
// baseline (212.565 us; speedup 1.0000x reference)
//
#include <hip/hip_runtime.h>
#include <hip/hip_bf16.h>

#define B_ 4
#define S_ 4096
#define DIN 1024
#define NS 4
#define KS 256
#define CHUNK 128
#define NCHUNK (S_/CHUNK)   // 32
#define INV16 0.0625f

typedef __bf16 bf16x8 __attribute__((ext_vector_type(8)));
typedef float f32x4 __attribute__((ext_vector_type(4)));

#define FENCE() asm volatile("" ::: "memory")
__device__ __forceinline__ void wait_vm8() { asm volatile("s_waitcnt vmcnt(8)" ::: "memory"); }
__device__ __forceinline__ void wait_vm4() { asm volatile("s_waitcnt vmcnt(4)" ::: "memory"); }
__device__ __forceinline__ void wait_vm0() { asm volatile("s_waitcnt vmcnt(0)" ::: "memory"); }
#define LGKM0() asm volatile("s_waitcnt lgkmcnt(0)" ::: "memory")

// ---------- bf16 helpers (raw ushort storage) ----------
__device__ __forceinline__ float b2f(unsigned short u) {
  union { unsigned int u; float f; } cv;
  cv.u = ((unsigned int)u) << 16;
  return cv.f;
}
__device__ __forceinline__ unsigned short f2b(float f) {
  union { float f; unsigned int u; } cv; cv.f = f;
  unsigned int u = cv.u;
  u += 0x7fffu + ((u >> 16) & 1u);   // round-to-nearest-even
  return (unsigned short)(u >> 16);
}

__device__ __forceinline__ void a_base_of(int n, float& ar, float& ai) {
  const float r[4]  = {1.0f, 0.999f, 0.9495f, 0.9f};
  const float th[4] = {0.0f, 0.01f, 0.505f, 1.0f};
  ar = r[n] * cosf(th[n]);
  ai = r[n] * sinf(th[n]);
}

__device__ __forceinline__ void glds16(const unsigned short* g, unsigned short* l) {
  __builtin_amdgcn_global_load_lds(
      (const __attribute__((address_space(1))) unsigned int*)g,
      (__attribute__((address_space(3))) unsigned int*)l, 16, 0, 0);
}

// ---------- merged conversion kernel ----------
__global__ __launch_bounds__(256) void cvt_all(const float* __restrict__ x,
                                               const float* __restrict__ Wg1,
                                               const float* __restrict__ Wre,
                                               const float* __restrict__ Wim,
                                               const float* __restrict__ Wg2,
                                               unsigned short* __restrict__ xb,
                                               unsigned short* __restrict__ Wb,
                                               unsigned short* __restrict__ Wg2t) {
  const int z = blockIdx.z;
  if (z >= 16) {
    const int blk = (z - 16)*256 + blockIdx.y*8 + blockIdx.x;   // 0..8191
    const size_t i = ((size_t)blk*256 + threadIdx.x)*8;
    const float4 v0 = *reinterpret_cast<const float4*>(x + i);
    const float4 v1 = *reinterpret_cast<const float4*>(x + i + 4);
    ushort4 o0, o1;
    o0.x=f2b(v0.x); o0.y=f2b(v0.y); o0.z=f2b(v0.z); o0.w=f2b(v0.w);
    o1.x=f2b(v1.x); o1.y=f2b(v1.y); o1.z=f2b(v1.z); o1.w=f2b(v1.w);
    *reinterpret_cast<ushort4*>(xb + i)     = o0;
    *reinterpret_cast<ushort4*>(xb + i + 4) = o1;
    return;
  }
  __shared__ float t[32][33];
  const int tx = threadIdx.x & 31, ty = threadIdx.x >> 5;
  const float* src;
  unsigned short* dst;
  int srcLD, dstLD;
  if (z < 12) {
    const int mat = z >> 2, n = z & 3;
    const float* W = (mat==0) ? Wg1 : (mat==1 ? Wre : Wim);
    src = W + (size_t)n*(DIN*KS);
    dst = Wb + (size_t)(mat*1024 + n*KS)*DIN;
    srcLD = KS; dstLD = DIN;
  } else {
    if (blockIdx.y >= 8) return;
    const int n = z - 12;
    src = Wg2 + (size_t)n*(KS*KS);
    dst = Wg2t + (size_t)n*(KS*KS);
    srcLD = KS; dstLD = KS;
  }
  const int r0 = blockIdx.y*32, c0 = blockIdx.x*32;
#pragma unroll
  for (int p = 0; p < 4; ++p)
    t[ty + p*8][tx] = src[(size_t)(r0 + ty + p*8)*srcLD + c0 + tx];
  __syncthreads();
#pragma unroll
  for (int p = 0; p < 4; ++p)
    dst[(size_t)(c0 + ty + p*8)*dstLD + r0 + tx] = f2b(t[tx][ty + p*8]);
}

// ================= 256x256 GEMM core, BK=32, 4-deep LDS buf + reg-dbuf frags =====
// Round-8 schedule + WAVE ANTI-PHASING: odd-group waves run MFMA-first segment
// order so the LDS pipe (reads) and matrix pipe (MFMA) overlap across waves
// instead of alternating in barrier lockstep.
typedef unsigned short LdsT[4][2][256][32];

template<int LDK>
__device__ __forceinline__ void stage_half(const unsigned short* __restrict__ gsrc,
                                           unsigned short* ldst, int tid, int kbase) {
#pragma unroll
  for (int i = 0; i < 2; ++i) {
    const int idx = i*512 + tid;           // 0..1023
    const int r  = idx >> 2;               // 0..255
    const int s  = idx & 3;                // physical 16B slot
    const int c8 = (s ^ ((r >> 1) & 3)) << 3;   // swizzled global column group
    glds16(gsrc + (size_t)r*LDK + kbase + c8, ldst + idx*8);
  }
}

#define DS_A(dst, buf, mg) do { _Pragma("unroll") \
  for (int m = 0; m < 4; ++m) \
    dst[m] = *(const bf16x8*)&lds[buf][0][wr*128 + (mg)*64 + m*16 + fr][(fq ^ swl)*8]; } while(0)
#define DS_B(dst, buf) do { _Pragma("unroll") \
  for (int n = 0; n < 4; ++n) \
    dst[n] = *(const bf16x8*)&lds[buf][1][wc*64 + n*16 + fr][(fq ^ swl)*8]; } while(0)
#define MFMA_ON(A_, B_, mg) do { __builtin_amdgcn_s_setprio(1); _Pragma("unroll") \
  for (int m = 0; m < 4; ++m) { _Pragma("unroll") \
    for (int n = 0; n < 4; ++n) \
      acc[(mg)*4+m][n] = __builtin_amdgcn_mfma_f32_16x16x32_bf16(A_[m], B_[n], acc[(mg)*4+m][n], 0, 0, 0); } \
  __builtin_amdgcn_s_setprio(0); } while(0)
#define BAR() do { FENCE(); __builtin_amdgcn_s_barrier(); FENCE(); } while(0)

// Shared wait tail: vm8 while >=3 stages in flight, vm4/vm0 at loop tail.
#define VMTAIL(T) do { \
  FENCE(); \
  if ((T)+3 < NT) wait_vm8(); else if ((T)+3 == NT) wait_vm4(); else wait_vm0(); \
  LGKM0(); \
  __builtin_amdgcn_s_barrier(); FENCE(); \
} while(0)

// EVEN order: [reads; stage; MFMA0] wait+bar [reads; MFMA1]
#define GSTEP_E(T, AC, AN, BC, BN) do { \
  const int _t = (T); \
  const int _nb = (_t+1) & 3; \
  DS_A(AN, (_t & 3), 1); \
  if (_t+3 < NT) { \
    stage_half<LDK>(gA, &lds[(_t+3)&3][0][0][0], tid, (_t+3)*32); \
    stage_half<LDK>(gB, &lds[(_t+3)&3][1][0][0], tid, (_t+3)*32); \
  } \
  MFMA_ON(AC, BC, 0); \
  VMTAIL(_t); \
  if (_t+1 < NT) { DS_A(AC, _nb, 0); DS_B(BN, _nb); } \
  MFMA_ON(AN, BC, 1); \
} while(0)

// ODD order: [MFMA0; reads; stage] wait+bar [MFMA1; reads]
// Legality: MFMA0's AC/BC were loaded in the previous step (compiler inserts
// the lgkm wait for the visible register dependence); MFMA1's AN loaded
// pre-barrier this step (covered by LGKM0); buffer-reuse invariant unchanged
// (all reads of buf X are issued before barrier X and covered by its LGKM0;
// the stage overwriting buf X issues after barrier X).
#define GSTEP_O(T, AC, AN, BC, BN) do { \
  const int _t = (T); \
  const int _nb = (_t+1) & 3; \
  MFMA_ON(AC, BC, 0); \
  DS_A(AN, (_t & 3), 1); \
  if (_t+3 < NT) { \
    stage_half<LDK>(gA, &lds[(_t+3)&3][0][0][0], tid, (_t+3)*32); \
    stage_half<LDK>(gB, &lds[(_t+3)&3][1][0][0], tid, (_t+3)*32); \
  } \
  VMTAIL(_t); \
  MFMA_ON(AN, BC, 1); \
  if (_t+1 < NT) { DS_A(AC, _nb, 0); DS_B(BN, _nb); } \
} while(0)

template<int LDK, int NT>
__device__ __forceinline__ void kloop256(const unsigned short* __restrict__ gA,
                                         const unsigned short* __restrict__ gB,
                                         LdsT& lds, int tid, int wr, int wc, int fr, int fq,
                                         f32x4 (&acc)[8][4]) {
  const int swl = (fr >> 1) & 3;
#pragma unroll
  for (int s = 0; s < 3; ++s) {
    stage_half<LDK>(gA, &lds[s][0][0][0], tid, s*32);
    stage_half<LDK>(gB, &lds[s][1][0][0], tid, s*32);
  }
  FENCE(); wait_vm8();
  __builtin_amdgcn_s_barrier(); FENCE();
  bf16x8 afa[4], afb[4], bfa[4], bfb[4];
  DS_A(afa, 0, 0); DS_B(bfa, 0);
  if ((((tid >> 6) >> 2) & 1) == 0) {
#pragma unroll 1
    for (int t = 0; t < NT; t += 2) {
      GSTEP_E(t,   afa, afb, bfa, bfb);
      GSTEP_E(t+1, afa, afb, bfb, bfa);
    }
  } else {
#pragma unroll 1
    for (int t = 0; t < NT; t += 2) {
      GSTEP_O(t,   afa, afb, bfa, bfb);
      GSTEP_O(t+1, afa, afb, bfb, bfa);
    }
  }
}

// ---------- GEMM1: C[16384][3072] = xb @ Wb^T -> g1/dre/dim ----------
__global__ __launch_bounds__(512, 1) void gemm1_8ph(
    const unsigned short* __restrict__ xb,   // [16384][1024]
    const unsigned short* __restrict__ Wb,   // [3072][1024]
    const float* __restrict__ bg1, const float* __restrict__ bre,
    const float* __restrict__ bim,
    unsigned short* __restrict__ g1, unsigned short* __restrict__ dre,
    unsigned short* __restrict__ dimv)
{
  __shared__ unsigned short lds[4][2][256][32];   // 128 KiB
  const int wg = blockIdx.x;                 // 768 = 8*96
  const int swz = (wg & 7)*96 + (wg >> 3);
  const int ct = swz % 12, rt = swz / 12;
  const int row0 = rt*256;
  const int tid = threadIdx.x, lane = tid & 63, wid = tid >> 6;
  const int wr = wid >> 2, wc = wid & 3, fr = lane & 15, fq = lane >> 4;

  const unsigned short* gA = xb + (size_t)row0*DIN;
  const unsigned short* gB = Wb + (size_t)(ct*256)*DIN;

  f32x4 acc[8][4];
#pragma unroll
  for (int m = 0; m < 8; ++m)
#pragma unroll
    for (int n = 0; n < 4; ++n) acc[m][n] = (f32x4){0.f,0.f,0.f,0.f};

  kloop256<DIN, DIN/32>(gA, gB, (LdsT&)lds, tid, wr, wc, fr, fq, acc);

  const int mat = ct >> 2, nsc = ct & 3;
  const float* bias = (mat==0) ? bg1 : (mat==1 ? bre : bim);
  unsigned short* dst = (mat==0) ? g1 : (mat==1 ? dre : dimv);

  // ---- epilogue: acc -> LDS (swizzled, conflict-free) -> vectorized stores ----
  BAR();   // all frag reads done before overlaying C on the staging LDS
  unsigned short (*C)[256] = reinterpret_cast<unsigned short(*)[256]>(&lds[0][0][0][0]);
#pragma unroll
  for (int mm = 0; mm < 8; ++mm) {
#pragma unroll
    for (int n = 0; n < 4; ++n) {
      const int ccol = wc*64 + n*16 + fr;
      const float bv = bias[nsc*KS + ccol];
#pragma unroll
      for (int reg = 0; reg < 4; ++reg) {
        const int r = wr*128 + mm*16 + fq*4 + reg;   // (r>>2)&3 == fq
        float v = acc[mm][n][reg] + bv;
        if (mat == 0) v = fmaxf(v, 0.f);
        C[r][ccol ^ (fq << 4)] = f2b(v);
      }
    }
  }
  __syncthreads();
#pragma unroll
  for (int i = 0; i < 16; ++i) {
    const int unit = i*512 + tid;
    const int r2 = unit >> 5;                 // 0..255
    const int g  = unit & 31;                 // 8-col group
    const int gp = g ^ (((r2 >> 2) & 3) << 1);
    const uint4 val = *reinterpret_cast<const uint4*>(&C[r2][gp*8]);
    const int grow = row0 + r2;
    const int bb2 = grow >> 12, s2 = grow & 4095;
    *reinterpret_cast<uint4*>(&dst[(((size_t)(bb2*NS + nsc))*S_ + s2)*KS + g*8]) = val;
  }
}

// ---------- GEMM2 + fused scan phase1 ----------
__global__ __launch_bounds__(512, 1) void gemm2_8ph(
    const unsigned short* __restrict__ g1,
    const unsigned short* __restrict__ Wg2t,   // [n][256 kout][256 kin]
    const float* __restrict__ bg2,
    const unsigned short* __restrict__ dre,
    const unsigned short* __restrict__ dimv,
    unsigned short* __restrict__ omg,
    float4* __restrict__ carry)                // [16 chains][32 chunks][256 k]
{
  __shared__ unsigned short lds[4][2][256][32];
  const int wg = blockIdx.x;                 // 256 = 8*32
  const int swz = (wg & 7)*32 + (wg >> 3);
  const int nz = swz >> 6, rowIdx = swz & 63;
  const int bb = rowIdx >> 4, st = rowIdx & 15;
  const int s0 = st*256;
  const int tid = threadIdx.x, lane = tid & 63, wid = tid >> 6;
  const int wr = wid >> 2, wc = wid & 3, fr = lane & 15, fq = lane >> 4;

  const unsigned short* gA = g1 + ((size_t)(bb*NS + nz)*S_ + s0)*KS;
  const unsigned short* gB = Wg2t + (size_t)nz*KS*KS;

  f32x4 acc[8][4];
#pragma unroll
  for (int m = 0; m < 8; ++m)
#pragma unroll
    for (int n = 0; n < 4; ++n) acc[m][n] = (f32x4){0.f,0.f,0.f,0.f};

  kloop256<KS, KS/32>(gA, gB, (LdsT&)lds, tid, wr, wc, fr, fq, acc);

  BAR();
  unsigned short (*C)[256] = reinterpret_cast<unsigned short(*)[256]>(&lds[0][0][0][0]);
#pragma unroll
  for (int mm = 0; mm < 8; ++mm) {
#pragma unroll
    for (int nn = 0; nn < 4; ++nn) {
      const int ccol = wc*64 + nn*16 + fr;
      const float bv = bg2[nz*KS + ccol];
#pragma unroll
      for (int reg = 0; reg < 4; ++reg) {
        const int r = wr*128 + mm*16 + fq*4 + reg;
        const float logit = acc[mm][nn][reg] + bv;
        const float gv = 1.0f / (1.0f + expf(logit));   // 1 - sigmoid
        C[r][ccol ^ (fq << 4)] = f2b(gv);
      }
    }
  }
  __syncthreads();
#pragma unroll
  for (int i = 0; i < 16; ++i) {
    const int unit = i*512 + tid;
    const int r2 = unit >> 5;
    const int g  = unit & 31;
    const int gp = g ^ (((r2 >> 2) & 3) << 1);
    const uint4 val = *reinterpret_cast<const uint4*>(&C[r2][gp*8]);
    *reinterpret_cast<uint4*>(&omg[(((size_t)(bb*NS + nz))*S_ + s0 + r2)*KS + g*8]) = val;
  }

  // ---- fused scan phase 1: per-chunk (A,B) aggregates ----
  const int ch = tid >> 8;                  // 0..1  (chunk within this 256-row tile)
  const int k  = tid & 255;
  const int chain = bb*NS + nz;
  const int c = st*2 + ch;                  // global chunk index 0..31
  float ar, ai; a_base_of(nz, ar, ai);
  const size_t gbase = ((size_t)chain*S_ + (size_t)(s0 + ch*CHUNK))*KS + k;
  float Are = 1.f, Aim = 0.f, Bre = 0.f, Bim = 0.f;
#pragma unroll 4
  for (int s = 0; s < CHUNK; ++s) {
    const int r = ch*CHUNK + s;
    const float g  = b2f(C[r][k ^ (((r >> 2) & 3) << 4)]);
    const size_t p = gbase + (size_t)s*KS;
    const float are = g*ar, aie = g*ai;
    const float br = g * b2f(dre[p])  * INV16;
    const float bi = g * b2f(dimv[p]) * INV16;
    const float nAre = Are*are - Aim*aie;
    const float nAim = Are*aie + Aim*are;
    const float nBre = fmaf(are, Bre, fmaf(-aie, Bim, br));
    const float nBim = fmaf(are, Bim, fmaf( aie, Bre, bi));
    Are = nAre; Aim = nAim; Bre = nBre; Bim = nBim;
  }
  carry[((size_t)chain*NCHUNK + c)*KS + k] = make_float4(Are, Aim, Bre, Bim);
}

// ---------- Scan phase 2: sequential carry over chunks per chain ----------
__global__ __launch_bounds__(256) void scan_carry(
    const float4* __restrict__ carry, float2* __restrict__ Hst)
{
  const int idx = blockIdx.x*256 + threadIdx.x;   // 0..4095
  const int k  = idx & 255;
  const int bn = idx >> 8;
  float hre = 0.f, him = 0.f;
  const size_t base = ((size_t)bn)*NCHUNK*KS + k;
  for (int c = 0; c < NCHUNK; ++c) {
    Hst[base + (size_t)c*KS] = make_float2(hre, him);
    const float4 ab = carry[base + (size_t)c*KS];
    const float nre = fmaf(ab.x, hre, fmaf(-ab.y, him, ab.z));
    const float nim = fmaf(ab.x, him, fmaf( ab.y, hre, ab.w));
    hre = nre; him = nim;
  }
}

// ---------- Scan phase 3: replay with chunk-entry state, write output ----------
__global__ __launch_bounds__(256) void scan_phase3(
    const unsigned short* __restrict__ omg,
    const unsigned short* __restrict__ dre,
    const unsigned short* __restrict__ dimv,
    const float2* __restrict__ Hst,
    float* __restrict__ out)
{
  const int c = blockIdx.x, n = blockIdx.y, bb = blockIdx.z;
  const int k = threadIdx.x;
  float ar, ai; a_base_of(n, ar, ai);
  const float2 h0 = Hst[(((size_t)(bb*NS + n))*NCHUNK + c)*KS + k];
  float hre = h0.x, him = h0.y;
  size_t base = (((size_t)(bb*NS + n))*S_ + (size_t)c*CHUNK)*KS + k;
  size_t ob = (((size_t)bb)*S_ + (size_t)c*CHUNK)*2048 + (size_t)n*512 + k;
#pragma unroll 4
  for (int s = 0; s < CHUNK; ++s) {
    const size_t p = base + (size_t)s*KS;
    const float g  = b2f(omg[p]);
    const float are = g*ar, aie = g*ai;
    const float br = g * b2f(dre[p])  * INV16;
    const float bi = g * b2f(dimv[p]) * INV16;
    const float nre = fmaf(are, hre, fmaf(-aie, him, br));
    const float nim = fmaf(are, him, fmaf( aie, hre, bi));
    hre = nre; him = nim;
    __builtin_nontemporal_store(hre, &out[ob + (size_t)s*2048      ]);
    __builtin_nontemporal_store(him, &out[ob + (size_t)s*2048 + 256]);
  }
}

extern "C" void kernel_launch(void* const* d_in, const int* in_sizes, int n_in,
                              void* d_out, int out_size, void* d_ws, size_t ws_size,
                              hipStream_t stream) {
  const float* x   = (const float*)d_in[0];
  const float* Wg1 = (const float*)d_in[1];
  const float* bg1 = (const float*)d_in[2];
  const float* Wg2 = (const float*)d_in[3];
  const float* bg2 = (const float*)d_in[4];
  const float* Wre = (const float*)d_in[5];
  const float* bre = (const float*)d_in[6];
  const float* Wim = (const float*)d_in[7];
  const float* bim = (const float*)d_in[8];
  float* out = (float*)d_out;

  char* ws = (char*)d_ws;
  const size_t BUF = (size_t)B_*NS*S_*KS*sizeof(unsigned short);  // 32 MiB
  unsigned short* g1   = (unsigned short*)(ws);
  unsigned short* dre  = (unsigned short*)(ws + BUF);
  unsigned short* dimv = (unsigned short*)(ws + 2*BUF);
  unsigned short* omg  = (unsigned short*)(ws + 3*BUF);
  unsigned short* xb   = (unsigned short*)(ws + 4*BUF);           // 32 MiB (gemm1 only)
  unsigned short* Wb   = (unsigned short*)(ws + 5*BUF);           // 6 MiB
  unsigned short* Wg2t = (unsigned short*)(ws + 5*BUF + (size_t)3072*1024*2);
  // scan scratch aliases xb's region (xb dead after gemm1)
  float4* carry = (float4*)(ws + 4*BUF);                          // 2 MiB
  float2* Hst   = (float2*)(ws + 4*BUF + (size_t)4*1024*1024);    // 1 MiB

  cvt_all<<<dim3(8, 32, 48), 256, 0, stream>>>(x, Wg1, Wre, Wim, Wg2, xb, Wb, Wg2t);

  gemm1_8ph<<<768, 512, 0, stream>>>(xb, Wb, bg1, bre, bim, g1, dre, dimv);
  gemm2_8ph<<<256, 512, 0, stream>>>(g1, Wg2t, bg2, dre, dimv, omg, carry);

  scan_carry<<<16, 256, 0, stream>>>(carry, Hst);
  scan_phase3<<<dim3(NCHUNK, NS, B_), 256, 0, stream>>>(omg, dre, dimv, Hst, out);
}

// Round 15
// 207.457 us; speedup vs baseline: 1.0246x; 1.0246x over previous
//
#include <hip/hip_runtime.h>
#include <hip/hip_bf16.h>

#define B_ 4
#define S_ 4096
#define DIN 1024
#define NS 4
#define KS 256
#define CHUNK 128
#define NCHUNK (S_/CHUNK)   // 32
#define INV16 0.0625f

typedef __bf16 bf16x8 __attribute__((ext_vector_type(8)));
typedef float f32x4 __attribute__((ext_vector_type(4)));

#define FENCE() asm volatile("" ::: "memory")
__device__ __forceinline__ void wait_vm8() { asm volatile("s_waitcnt vmcnt(8)" ::: "memory"); }
__device__ __forceinline__ void wait_vm4() { asm volatile("s_waitcnt vmcnt(4)" ::: "memory"); }
__device__ __forceinline__ void wait_vm0() { asm volatile("s_waitcnt vmcnt(0)" ::: "memory"); }
#define LGKM0() asm volatile("s_waitcnt lgkmcnt(0)" ::: "memory")

// ---------- bf16 helpers (raw ushort storage) ----------
__device__ __forceinline__ float b2f(unsigned short u) {
  union { unsigned int u; float f; } cv;
  cv.u = ((unsigned int)u) << 16;
  return cv.f;
}
__device__ __forceinline__ unsigned short f2b(float f) {
  union { float f; unsigned int u; } cv; cv.f = f;
  unsigned int u = cv.u;
  u += 0x7fffu + ((u >> 16) & 1u);   // round-to-nearest-even
  return (unsigned short)(u >> 16);
}

__device__ __forceinline__ void a_base_of(int n, float& ar, float& ai) {
  const float r[4]  = {1.0f, 0.999f, 0.9495f, 0.9f};
  const float th[4] = {0.0f, 0.01f, 0.505f, 1.0f};
  ar = r[n] * cosf(th[n]);
  ai = r[n] * sinf(th[n]);
}

__device__ __forceinline__ void glds16(const unsigned short* g, unsigned short* l) {
  __builtin_amdgcn_global_load_lds(
      (const __attribute__((address_space(1))) unsigned int*)g,
      (__attribute__((address_space(3))) unsigned int*)l, 16, 0, 0);
}

// ---------- merged conversion kernel ----------
// z<12 : W1[mat][n][1024 d][256 k] fp32 -> Wb[mat*1024+n*256+k][1024 d] bf16
// z=12..15 : Wg2[n][256][256] fp32 -> Wg2t[n][256 kout][256 kin] bf16 (y<8 only)
// z>=16 : x fp32 -> xb bf16 (linear chunks)
__global__ __launch_bounds__(256) void cvt_all(const float* __restrict__ x,
                                               const float* __restrict__ Wg1,
                                               const float* __restrict__ Wre,
                                               const float* __restrict__ Wim,
                                               const float* __restrict__ Wg2,
                                               unsigned short* __restrict__ xb,
                                               unsigned short* __restrict__ Wb,
                                               unsigned short* __restrict__ Wg2t) {
  const int z = blockIdx.z;
  if (z >= 16) {
    const int blk = (z - 16)*256 + blockIdx.y*8 + blockIdx.x;   // 0..8191
    const size_t i = ((size_t)blk*256 + threadIdx.x)*8;
    const float4 v0 = *reinterpret_cast<const float4*>(x + i);
    const float4 v1 = *reinterpret_cast<const float4*>(x + i + 4);
    ushort4 o0, o1;
    o0.x=f2b(v0.x); o0.y=f2b(v0.y); o0.z=f2b(v0.z); o0.w=f2b(v0.w);
    o1.x=f2b(v1.x); o1.y=f2b(v1.y); o1.z=f2b(v1.z); o1.w=f2b(v1.w);
    *reinterpret_cast<ushort4*>(xb + i)     = o0;
    *reinterpret_cast<ushort4*>(xb + i + 4) = o1;
    return;
  }
  __shared__ float t[32][33];
  const int tx = threadIdx.x & 31, ty = threadIdx.x >> 5;
  const float* src;
  unsigned short* dst;
  int srcLD, dstLD;
  if (z < 12) {
    const int mat = z >> 2, n = z & 3;
    const float* W = (mat==0) ? Wg1 : (mat==1 ? Wre : Wim);
    src = W + (size_t)n*(DIN*KS);
    dst = Wb + (size_t)(mat*1024 + n*KS)*DIN;
    srcLD = KS; dstLD = DIN;
  } else {
    if (blockIdx.y >= 8) return;
    const int n = z - 12;
    src = Wg2 + (size_t)n*(KS*KS);
    dst = Wg2t + (size_t)n*(KS*KS);
    srcLD = KS; dstLD = KS;
  }
  const int r0 = blockIdx.y*32, c0 = blockIdx.x*32;
#pragma unroll
  for (int p = 0; p < 4; ++p)
    t[ty + p*8][tx] = src[(size_t)(r0 + ty + p*8)*srcLD + c0 + tx];
  __syncthreads();
#pragma unroll
  for (int p = 0; p < 4; ++p)
    dst[(size_t)(c0 + ty + p*8)*dstLD + r0 + tx] = f2b(t[tx][ty + p*8]);
}

// ================= 256x256 GEMM core, BK=32, 4-deep LDS buf + reg-dbuf frags =====
// (round-8 schedule: best measured — 104.6 us, MfmaUtil 44%)
typedef unsigned short LdsT[4][2][256][32];

template<int LDK>
__device__ __forceinline__ void stage_half(const unsigned short* __restrict__ gsrc,
                                           unsigned short* ldst, int tid, int kbase) {
#pragma unroll
  for (int i = 0; i < 2; ++i) {
    const int idx = i*512 + tid;           // 0..1023
    const int r  = idx >> 2;               // 0..255
    const int s  = idx & 3;                // physical 16B slot
    const int c8 = (s ^ ((r >> 1) & 3)) << 3;   // swizzled global column group
    glds16(gsrc + (size_t)r*LDK + kbase + c8, ldst + idx*8);
  }
}

#define DS_A(dst, buf, mg) do { _Pragma("unroll") \
  for (int m = 0; m < 4; ++m) \
    dst[m] = *(const bf16x8*)&lds[buf][0][wr*128 + (mg)*64 + m*16 + fr][(fq ^ swl)*8]; } while(0)
#define DS_B(dst, buf) do { _Pragma("unroll") \
  for (int n = 0; n < 4; ++n) \
    dst[n] = *(const bf16x8*)&lds[buf][1][wc*64 + n*16 + fr][(fq ^ swl)*8]; } while(0)
#define MFMA_ON(A_, B_, mg) do { __builtin_amdgcn_s_setprio(1); _Pragma("unroll") \
  for (int m = 0; m < 4; ++m) { _Pragma("unroll") \
    for (int n = 0; n < 4; ++n) \
      acc[(mg)*4+m][n] = __builtin_amdgcn_mfma_f32_16x16x32_bf16(A_[m], B_[n], acc[(mg)*4+m][n], 0, 0, 0); } \
  __builtin_amdgcn_s_setprio(0); } while(0)
#define BAR() do { FENCE(); __builtin_amdgcn_s_barrier(); FENCE(); } while(0)

#define GSTEP(T, AC, AN, BC, BN) do { \
  const int _t = (T); \
  const int _nb = (_t+1) & 3; \
  DS_A(AN, (_t & 3), 1); \
  if (_t+3 < NT) { \
    stage_half<LDK>(gA, &lds[(_t+3)&3][0][0][0], tid, (_t+3)*32); \
    stage_half<LDK>(gB, &lds[(_t+3)&3][1][0][0], tid, (_t+3)*32); \
  } \
  MFMA_ON(AC, BC, 0); \
  FENCE(); \
  if (_t+3 < NT) wait_vm8(); else if (_t+3 == NT) wait_vm4(); else wait_vm0(); \
  LGKM0(); \
  __builtin_amdgcn_s_barrier(); FENCE(); \
  if (_t+1 < NT) { DS_A(AC, _nb, 0); DS_B(BN, _nb); } \
  MFMA_ON(AN, BC, 1); \
} while(0)

template<int LDK, int NT>
__device__ __forceinline__ void kloop256(const unsigned short* __restrict__ gA,
                                         const unsigned short* __restrict__ gB,
                                         LdsT& lds, int tid, int wr, int wc, int fr, int fq,
                                         f32x4 (&acc)[8][4]) {
  const int swl = (fr >> 1) & 3;
#pragma unroll
  for (int s = 0; s < 3; ++s) {
    stage_half<LDK>(gA, &lds[s][0][0][0], tid, s*32);
    stage_half<LDK>(gB, &lds[s][1][0][0], tid, s*32);
  }
  FENCE(); wait_vm8();
  __builtin_amdgcn_s_barrier(); FENCE();
  bf16x8 afa[4], afb[4], bfa[4], bfb[4];
  DS_A(afa, 0, 0); DS_B(bfa, 0);
#pragma unroll 1
  for (int t = 0; t < NT; t += 2) {
    GSTEP(t,   afa, afb, bfa, bfb);
    GSTEP(t+1, afa, afb, bfb, bfa);
  }
}

// ---------- GEMM1: C[16384][3072] = xb @ Wb^T -> g1/dre/dim ----------
__global__ __launch_bounds__(512, 1) void gemm1_8ph(
    const unsigned short* __restrict__ xb,   // [16384][1024]
    const unsigned short* __restrict__ Wb,   // [3072][1024]
    const float* __restrict__ bg1, const float* __restrict__ bre,
    const float* __restrict__ bim,
    unsigned short* __restrict__ g1, unsigned short* __restrict__ dre,
    unsigned short* __restrict__ dimv)
{
  __shared__ unsigned short lds[4][2][256][32];   // 128 KiB
  const int wg = blockIdx.x;                 // 768 = 8*96
  const int swz = (wg & 7)*96 + (wg >> 3);
  const int ct = swz % 12, rt = swz / 12;
  const int row0 = rt*256;
  const int tid = threadIdx.x, lane = tid & 63, wid = tid >> 6;
  const int wr = wid >> 2, wc = wid & 3, fr = lane & 15, fq = lane >> 4;

  const unsigned short* gA = xb + (size_t)row0*DIN;
  const unsigned short* gB = Wb + (size_t)(ct*256)*DIN;

  f32x4 acc[8][4];
#pragma unroll
  for (int m = 0; m < 8; ++m)
#pragma unroll
    for (int n = 0; n < 4; ++n) acc[m][n] = (f32x4){0.f,0.f,0.f,0.f};

  kloop256<DIN, DIN/32>(gA, gB, (LdsT&)lds, tid, wr, wc, fr, fq, acc);

  const int mat = ct >> 2, nsc = ct & 3;
  const float* bias = (mat==0) ? bg1 : (mat==1 ? bre : bim);
  unsigned short* dst = (mat==0) ? g1 : (mat==1 ? dre : dimv);

  // ---- epilogue: acc -> LDS (swizzled, conflict-free) -> vectorized stores ----
  BAR();   // all frag reads done before overlaying C on the staging LDS
  unsigned short (*C)[256] = reinterpret_cast<unsigned short(*)[256]>(&lds[0][0][0][0]);
#pragma unroll
  for (int mm = 0; mm < 8; ++mm) {
#pragma unroll
    for (int n = 0; n < 4; ++n) {
      const int ccol = wc*64 + n*16 + fr;
      const float bv = bias[nsc*KS + ccol];
#pragma unroll
      for (int reg = 0; reg < 4; ++reg) {
        const int r = wr*128 + mm*16 + fq*4 + reg;   // (r>>2)&3 == fq
        float v = acc[mm][n][reg] + bv;
        if (mat == 0) v = fmaxf(v, 0.f);
        C[r][ccol ^ (fq << 4)] = f2b(v);
      }
    }
  }
  __syncthreads();
#pragma unroll
  for (int i = 0; i < 16; ++i) {
    const int unit = i*512 + tid;
    const int r2 = unit >> 5;                 // 0..255
    const int g  = unit & 31;                 // 8-col group
    const int gp = g ^ (((r2 >> 2) & 3) << 1);
    const uint4 val = *reinterpret_cast<const uint4*>(&C[r2][gp*8]);
    const int grow = row0 + r2;
    const int bb2 = grow >> 12, s2 = grow & 4095;
    *reinterpret_cast<uint4*>(&dst[(((size_t)(bb2*NS + nsc))*S_ + s2)*KS + g*8]) = val;
  }
}

// ---------- GEMM2 + fused scan phase1 ----------
__global__ __launch_bounds__(512, 1) void gemm2_8ph(
    const unsigned short* __restrict__ g1,
    const unsigned short* __restrict__ Wg2t,   // [n][256 kout][256 kin]
    const float* __restrict__ bg2,
    const unsigned short* __restrict__ dre,
    const unsigned short* __restrict__ dimv,
    unsigned short* __restrict__ omg,
    float4* __restrict__ carry)                // [16 chains][32 chunks][256 k]
{
  __shared__ unsigned short lds[4][2][256][32];
  const int wg = blockIdx.x;                 // 256 = 8*32
  const int swz = (wg & 7)*32 + (wg >> 3);
  const int nz = swz >> 6, rowIdx = swz & 63;
  const int bb = rowIdx >> 4, st = rowIdx & 15;
  const int s0 = st*256;
  const int tid = threadIdx.x, lane = tid & 63, wid = tid >> 6;
  const int wr = wid >> 2, wc = wid & 3, fr = lane & 15, fq = lane >> 4;

  const unsigned short* gA = g1 + ((size_t)(bb*NS + nz)*S_ + s0)*KS;
  const unsigned short* gB = Wg2t + (size_t)nz*KS*KS;

  f32x4 acc[8][4];
#pragma unroll
  for (int m = 0; m < 8; ++m)
#pragma unroll
    for (int n = 0; n < 4; ++n) acc[m][n] = (f32x4){0.f,0.f,0.f,0.f};

  kloop256<KS, KS/32>(gA, gB, (LdsT&)lds, tid, wr, wc, fr, fq, acc);

  BAR();
  unsigned short (*C)[256] = reinterpret_cast<unsigned short(*)[256]>(&lds[0][0][0][0]);
#pragma unroll
  for (int mm = 0; mm < 8; ++mm) {
#pragma unroll
    for (int nn = 0; nn < 4; ++nn) {
      const int ccol = wc*64 + nn*16 + fr;
      const float bv = bg2[nz*KS + ccol];
#pragma unroll
      for (int reg = 0; reg < 4; ++reg) {
        const int r = wr*128 + mm*16 + fq*4 + reg;
        const float logit = acc[mm][nn][reg] + bv;
        const float gv = 1.0f / (1.0f + expf(logit));   // 1 - sigmoid
        C[r][ccol ^ (fq << 4)] = f2b(gv);
      }
    }
  }
  __syncthreads();
#pragma unroll
  for (int i = 0; i < 16; ++i) {
    const int unit = i*512 + tid;
    const int r2 = unit >> 5;
    const int g  = unit & 31;
    const int gp = g ^ (((r2 >> 2) & 3) << 1);
    const uint4 val = *reinterpret_cast<const uint4*>(&C[r2][gp*8]);
    *reinterpret_cast<uint4*>(&omg[(((size_t)(bb*NS + nz))*S_ + s0 + r2)*KS + g*8]) = val;
  }

  // ---- fused scan phase 1: per-chunk (A,B) aggregates ----
  const int ch = tid >> 8;                  // 0..1  (chunk within this 256-row tile)
  const int k  = tid & 255;
  const int chain = bb*NS + nz;
  const int c = st*2 + ch;                  // global chunk index 0..31
  float ar, ai; a_base_of(nz, ar, ai);
  const size_t gbase = ((size_t)chain*S_ + (size_t)(s0 + ch*CHUNK))*KS + k;
  float Are = 1.f, Aim = 0.f, Bre = 0.f, Bim = 0.f;
#pragma unroll 4
  for (int s = 0; s < CHUNK; ++s) {
    const int r = ch*CHUNK + s;
    const float g  = b2f(C[r][k ^ (((r >> 2) & 3) << 4)]);
    const size_t p = gbase + (size_t)s*KS;
    const float are = g*ar, aie = g*ai;
    const float br = g * b2f(dre[p])  * INV16;
    const float bi = g * b2f(dimv[p]) * INV16;
    const float nAre = Are*are - Aim*aie;
    const float nAim = Are*aie + Aim*are;
    const float nBre = fmaf(are, Bre, fmaf(-aie, Bim, br));
    const float nBim = fmaf(are, Bim, fmaf( aie, Bre, bi));
    Are = nAre; Aim = nAim; Bre = nBre; Bim = nBim;
  }
  carry[((size_t)chain*NCHUNK + c)*KS + k] = make_float4(Are, Aim, Bre, Bim);
}

// ---------- Scan phase 2: sequential carry over chunks per chain ----------
__global__ __launch_bounds__(256) void scan_carry(
    const float4* __restrict__ carry, float2* __restrict__ Hst)
{
  const int idx = blockIdx.x*256 + threadIdx.x;   // 0..4095
  const int k  = idx & 255;
  const int bn = idx >> 8;
  float hre = 0.f, him = 0.f;
  const size_t base = ((size_t)bn)*NCHUNK*KS + k;
  for (int c = 0; c < NCHUNK; ++c) {
    Hst[base + (size_t)c*KS] = make_float2(hre, him);
    const float4 ab = carry[base + (size_t)c*KS];
    const float nre = fmaf(ab.x, hre, fmaf(-ab.y, him, ab.z));
    const float nim = fmaf(ab.x, him, fmaf( ab.y, hre, ab.w));
    hre = nre; him = nim;
  }
}

// ---------- Scan phase 3: replay with chunk-entry state, write output ----------
__global__ __launch_bounds__(256) void scan_phase3(
    const unsigned short* __restrict__ omg,
    const unsigned short* __restrict__ dre,
    const unsigned short* __restrict__ dimv,
    const float2* __restrict__ Hst,
    float* __restrict__ out)
{
  const int c = blockIdx.x, n = blockIdx.y, bb = blockIdx.z;
  const int k = threadIdx.x;
  float ar, ai; a_base_of(n, ar, ai);
  const float2 h0 = Hst[(((size_t)(bb*NS + n))*NCHUNK + c)*KS + k];
  float hre = h0.x, him = h0.y;
  size_t base = (((size_t)(bb*NS + n))*S_ + (size_t)c*CHUNK)*KS + k;
  size_t ob = (((size_t)bb)*S_ + (size_t)c*CHUNK)*2048 + (size_t)n*512 + k;
#pragma unroll 4
  for (int s = 0; s < CHUNK; ++s) {
    const size_t p = base + (size_t)s*KS;
    const float g  = b2f(omg[p]);
    const float are = g*ar, aie = g*ai;
    const float br = g * b2f(dre[p])  * INV16;
    const float bi = g * b2f(dimv[p]) * INV16;
    const float nre = fmaf(are, hre, fmaf(-aie, him, br));
    const float nim = fmaf(are, him, fmaf( aie, hre, bi));
    hre = nre; him = nim;
    __builtin_nontemporal_store(hre, &out[ob + (size_t)s*2048      ]);
    __builtin_nontemporal_store(him, &out[ob + (size_t)s*2048 + 256]);
  }
}

extern "C" void kernel_launch(void* const* d_in, const int* in_sizes, int n_in,
                              void* d_out, int out_size, void* d_ws, size_t ws_size,
                              hipStream_t stream) {
  const float* x   = (const float*)d_in[0];
  const float* Wg1 = (const float*)d_in[1];
  const float* bg1 = (const float*)d_in[2];
  const float* Wg2 = (const float*)d_in[3];
  const float* bg2 = (const float*)d_in[4];
  const float* Wre = (const float*)d_in[5];
  const float* bre = (const float*)d_in[6];
  const float* Wim = (const float*)d_in[7];
  const float* bim = (const float*)d_in[8];
  float* out = (float*)d_out;

  char* ws = (char*)d_ws;
  const size_t BUF = (size_t)B_*NS*S_*KS*sizeof(unsigned short);  // 32 MiB
  unsigned short* g1   = (unsigned short*)(ws);
  unsigned short* dre  = (unsigned short*)(ws + BUF);
  unsigned short* dimv = (unsigned short*)(ws + 2*BUF);
  unsigned short* omg  = (unsigned short*)(ws + 3*BUF);
  unsigned short* xb   = (unsigned short*)(ws + 4*BUF);           // 32 MiB (gemm1 only)
  unsigned short* Wb   = (unsigned short*)(ws + 5*BUF);           // 6 MiB
  unsigned short* Wg2t = (unsigned short*)(ws + 5*BUF + (size_t)3072*1024*2);
  // scan scratch aliases xb's region (xb dead after gemm1)
  float4* carry = (float4*)(ws + 4*BUF);                          // 2 MiB
  float2* Hst   = (float2*)(ws + 4*BUF + (size_t)4*1024*1024);    // 1 MiB

  cvt_all<<<dim3(8, 32, 48), 256, 0, stream>>>(x, Wg1, Wre, Wim, Wg2, xb, Wb, Wg2t);

  gemm1_8ph<<<768, 512, 0, stream>>>(xb, Wb, bg1, bre, bim, g1, dre, dimv);
  gemm2_8ph<<<256, 512, 0, stream>>>(g1, Wg2t, bg2, dre, dimv, omg, carry);

  scan_carry<<<16, 256, 0, stream>>>(carry, Hst);
  scan_phase3<<<dim3(NCHUNK, NS, B_), 256, 0, stream>>>(omg, dre, dimv, Hst, out);
}